// Round 16
// baseline (659.670 us; speedup 1.0000x reference)
//
#include <hip/hip_runtime.h>
#include <hip/hip_fp16.h>

#define NFEAT 128
#define NHID 64
#define NOUT 128
#define NHEADS 8
#define ALPHA_SLOPE 0.2f
#define EPS_DENOM 1e-16f

#define MAXNB 1024
#define BIN_EPB 12288
#define BIN_CAP 6144

typedef _Float16 f16;
typedef f16 f16x2 __attribute__((ext_vector_type(2)));
typedef f16 f16x8 __attribute__((ext_vector_type(8)));
typedef float f32x4 __attribute__((ext_vector_type(4)));

static __device__ __forceinline__ float elu_f(float v) {
  return v > 0.f ? v : __expf(v) - 1.f;
}
static __device__ __forceinline__ float edge_w(float sc) {
  float lr = sc > 0.f ? sc : ALPHA_SLOPE * sc;
  return __expf(-lr);
}
static __device__ __forceinline__ f16x2 u2h(unsigned int u) {
  union { unsigned int u; f16x2 h; } c; c.u = u; return c.h;
}
static __device__ __forceinline__ float dot2f(f16x2 a, f16x2 b, float c) {
#if __has_builtin(__builtin_amdgcn_fdot2)
  return __builtin_amdgcn_fdot2(a, b, c, false);
#else
  return c + (float)a[0] * (float)b[0] + (float)a[1] * (float)b[1];
#endif
}

// region 0: W1 [8][128][64] -> w1t [8][64][128] fp16; region 1: W2 -> w2t [128][512] fp16;
// region 2: uv16[16][128] = {W1[h]@a1[h][:64], W1[h]@a1[h][64:]} (score identity)
__global__ void k_cvt_w(const float* __restrict__ W1, const float* __restrict__ W2,
                        const float* __restrict__ a1,
                        f16* __restrict__ w1t, f16* __restrict__ w2t,
                        f16* __restrict__ uv16) {
  int idx = blockIdx.x * 256 + threadIdx.x;
  if (idx < NHEADS * 128 * 64) {
    int h = idx >> 13, rem = idx & 8191, c = rem >> 7, k = rem & 127;
    w1t[idx] = (f16)W1[h * 8192 + k * 64 + c];
  } else if (idx < 2 * NHEADS * 128 * 64) {
    int j = idx - NHEADS * 128 * 64;
    int c = j >> 9, k = j & 511;
    w2t[j] = (f16)W2[k * 128 + c];
  } else {
    int id = idx - 2 * NHEADS * 128 * 64;
    if (id < 1024) {
      int h = id >> 7, k = id & 127;
      const float* wrow = W1 + h * 8192 + k * 64;
      const float* ah = a1 + h * 128;
      float u = 0.f, v = 0.f;
      for (int c = 0; c < 64; ++c) {
        float wv_ = wrow[c];
        u += wv_ * ah[c];
        v += wv_ * ah[64 + c];
      }
      uv16[h * 128 + k] = (f16)u;
      uv16[(8 + h) * 128 + k] = (f16)v;
    }
  }
}

// fused: x f32 -> xh fp16 AND [N,128]@[128,16] MFMA -> ssrc8 f32 / sdst8h fp16
__global__ __launch_bounds__(256) void k_prep_x(
    const float* __restrict__ x, const f16* __restrict__ uv16,
    f16* __restrict__ xh, float* __restrict__ ssrc8, f16* __restrict__ sdst8h, int N) {
  int wave = threadIdx.x >> 6, lane = threadIdx.x & 63;
  int c = lane & 15, g = lane >> 4;
  int row0 = blockIdx.x * 64 + wave * 16;
  f16x8 bf[4];
#pragma unroll
  for (int ks = 0; ks < 4; ++ks)
    bf[ks] = *(const f16x8*)(uv16 + c * 128 + ks * 32 + g * 8);
  int arow = row0 + c; if (arow > N - 1) arow = N - 1;
  const float* xp = x + (size_t)arow * 128 + g * 8;
  f16* xhp = xh + (size_t)arow * 128 + g * 8;
  f32x4 acc = (f32x4){0.f, 0.f, 0.f, 0.f};
#pragma unroll
  for (int ks = 0; ks < 4; ++ks) {
    float4 v0 = *(const float4*)(xp + ks * 32);
    float4 v1 = *(const float4*)(xp + ks * 32 + 4);
    f16x8 af;
    af[0] = (f16)v0.x; af[1] = (f16)v0.y; af[2] = (f16)v0.z; af[3] = (f16)v0.w;
    af[4] = (f16)v1.x; af[5] = (f16)v1.y; af[6] = (f16)v1.z; af[7] = (f16)v1.w;
    *(f16x8*)(xhp + ks * 32) = af;   // duplicate tail writes benign (same data)
    acc = __builtin_amdgcn_mfma_f32_16x16x32_f16(af, bf[ks], acc, 0, 0, 0);
  }
#pragma unroll
  for (int j = 0; j < 4; ++j) {
    int r = row0 + g * 4 + j;
    if (r < N) {
      if (c < 8) ssrc8[(size_t)r * 8 + c] = acc[j];
      else       sdst8h[(size_t)r * 8 + c - 8] = (f16)acc[j];
    }
  }
}

// ---------------- CSR build: 2-pass bucketed counting sort ----------------
__global__ __launch_bounds__(256) void k_bhist(const int* __restrict__ src,
                                               int* __restrict__ bhist,
                                               int E, int NB, int shift) {
  __shared__ int h[MAXNB];
  int tid = threadIdx.x;
  for (int i = tid; i < NB; i += 256) h[i] = 0;
  __syncthreads();
  int base = blockIdx.x * BIN_EPB;
#pragma unroll 4
  for (int j = 0; j < BIN_EPB / 256; ++j) {
    int e = base + tid + j * 256;
    if (e < E) atomicAdd(&h[src[e] >> shift], 1);
  }
  __syncthreads();
  for (int i = tid; i < NB; i += 256)
    if (h[i]) atomicAdd(&bhist[i], h[i]);
}

__global__ __launch_bounds__(1024) void k_bscan(const int* __restrict__ bhist,
                                                int* __restrict__ bucket_base,
                                                int* __restrict__ bucket_cursor,
                                                int* __restrict__ rp,
                                                int NB, int N, int E) {
  __shared__ int sh[1024];
  int i = threadIdx.x;
  int v = (i < NB) ? bhist[i] : 0;
  sh[i] = v;
  __syncthreads();
  for (int off = 1; off < 1024; off <<= 1) {
    int add = (i >= off) ? sh[i - off] : 0;
    __syncthreads();
    sh[i] += add;
    __syncthreads();
  }
  if (i < NB) {
    int ex = sh[i] - v;
    bucket_base[i] = ex;
    bucket_cursor[i] = ex;
  }
  if (i == 0) {
    bucket_base[NB] = E;
    rp[N] = E;
  }
}

__global__ __launch_bounds__(256) void k_binA(const int* __restrict__ src,
                                              const int* __restrict__ dst,
                                              int* __restrict__ bucket_cursor,
                                              int2* __restrict__ staging,
                                              int E, int NB, int shift) {
  __shared__ int h[MAXNB];
  int tid = threadIdx.x;
  for (int i = tid; i < NB; i += 256) h[i] = 0;
  __syncthreads();
  int base = blockIdx.x * BIN_EPB;
#pragma unroll 4
  for (int j = 0; j < BIN_EPB / 256; ++j) {
    int e = base + tid + j * 256;
    if (e < E) atomicAdd(&h[src[e] >> shift], 1);
  }
  __syncthreads();
  for (int i = tid; i < NB; i += 256)
    if (h[i]) h[i] = atomicAdd(&bucket_cursor[i], h[i]);
  __syncthreads();
#pragma unroll 4
  for (int j = 0; j < BIN_EPB / 256; ++j) {
    int e = base + tid + j * 256;
    if (e < E) {
      int s = src[e];
      int slot = atomicAdd(&h[s >> shift], 1);
      staging[slot] = make_int2(s, dst[e]);
    }
  }
}

__global__ __launch_bounds__(256) void k_binB(const int2* __restrict__ staging,
                                              const int* __restrict__ bucket_base,
                                              int* __restrict__ rp,
                                              int* __restrict__ edge_dst,
                                              int N, int shift) {
  __shared__ int2 buf[BIN_CAP];
  __shared__ int rcnt[256], rsc[256];
  int tid = threadIdx.x;
  int b = blockIdx.x;
  int lo = bucket_base[b], hi = bucket_base[b + 1];
  int S = hi - lo;
  if (S > BIN_CAP) S = BIN_CAP;
  int R = 1 << shift;
  int rmask = R - 1;
  for (int i = tid; i < S; i += 256) buf[i] = staging[lo + i];
  if (tid < R) rcnt[tid] = 0;
  __syncthreads();
  for (int i = tid; i < S; i += 256) atomicAdd(&rcnt[buf[i].x & rmask], 1);
  __syncthreads();
  if (tid < R) rsc[tid] = rcnt[tid];
  __syncthreads();
  for (int off = 1; off < 256; off <<= 1) {
    int add = (tid >= off && tid < R) ? rsc[tid - off] : 0;
    __syncthreads();
    if (tid < R) rsc[tid] += add;
    __syncthreads();
  }
  int row0 = b << shift;
  if (tid < R) {
    int ex = rsc[tid] - rcnt[tid];
    rcnt[tid] = ex;
    if (row0 + tid < N) rp[row0 + tid] = lo + ex;
  }
  __syncthreads();
  for (int i = tid; i < S; i += 256) {
    int r = buf[i].x & rmask;
    int k = atomicAdd(&rcnt[r], 1);
    edge_dst[lo + k] = buf[i].y;
  }
}

// ---------------- layer-1 shared-x aggregation: ALL 8 heads, dot2 + 8B/lane gather ----
// wave per node. phase1: lane=edge computes 8 weights -> transposed LDS wT[head][edge].
// phase2: half-wave hi owns edges (jj+2hi, jj+2hi+1); lane covers 4 cols (8B x-load);
// v_perm interleaves the edge pair into half2; v_dot2 accumulates 2 edges/inst.
__global__ __launch_bounds__(256) void k_aggx(
    const int* __restrict__ rp, const int* __restrict__ edge_dst,
    const f16* __restrict__ xh, const float* __restrict__ ssrc8,
    const f16* __restrict__ sdst8h, f16* __restrict__ msgx, int c0, int c1) {
  __shared__ __half wT[4][8][72];   // per-wave transposed weights; 72 = 64 + 8 pad
  int wave = threadIdx.x >> 6;
  int lane = threadIdx.x & 63;
  int node = c0 + blockIdx.x * 4 + wave;
  if (node >= c1) return;             // safe: no __syncthreads below
  int e0 = rp[node], e1 = rp[node + 1];
  int hi = lane >> 5, li = lane & 31;
  int col4 = li * 4;                  // 4 columns per lane
  float4 sA = *(const float4*)(ssrc8 + (size_t)node * 8);
  float4 sB = *(const float4*)(ssrc8 + (size_t)node * 8 + 4);
  float acc[8][4];
#pragma unroll
  for (int h = 0; h < 8; ++h)
#pragma unroll
    for (int cc = 0; cc < 4; ++cc) acc[h][cc] = 0.f;
  float rs[8];
#pragma unroll
  for (int h = 0; h < 8; ++h) rs[h] = 0.f;
  __half* wb = &wT[wave][0][0];   // head stride 72

  for (int base = e0; base < e1; base += 64) {
    int cnt = e1 - base; if (cnt > 64) cnt = 64;
    int d = 0;
    float w0 = 0.f, w1 = 0.f, w2 = 0.f, w3 = 0.f, w4 = 0.f, w5 = 0.f, w6 = 0.f, w7 = 0.f;
    if (lane < cnt) {
      d = edge_dst[base + lane];
      f16x8 dv = *(const f16x8*)(sdst8h + (size_t)d * 8);
      w0 = edge_w(sA.x + (float)dv[0]); w1 = edge_w(sA.y + (float)dv[1]);
      w2 = edge_w(sA.z + (float)dv[2]); w3 = edge_w(sA.w + (float)dv[3]);
      w4 = edge_w(sB.x + (float)dv[4]); w5 = edge_w(sB.y + (float)dv[5]);
      w6 = edge_w(sB.z + (float)dv[6]); w7 = edge_w(sB.w + (float)dv[7]);
      rs[0] += w0; rs[1] += w1; rs[2] += w2; rs[3] += w3;
      rs[4] += w4; rs[5] += w5; rs[6] += w6; rs[7] += w7;
    }
    wb[0 * 72 + lane] = __float2half(w0);
    wb[1 * 72 + lane] = __float2half(w1);
    wb[2 * 72 + lane] = __float2half(w2);
    wb[3 * 72 + lane] = __float2half(w3);
    wb[4 * 72 + lane] = __float2half(w4);
    wb[5 * 72 + lane] = __float2half(w5);
    wb[6 * 72 + lane] = __float2half(w6);
    wb[7 * 72 + lane] = __float2half(w7);
    __threadfence_block();            // order per-wave LDS write -> read

    int jj = 0;
    for (; jj + 4 <= cnt; jj += 4) {
      int ea = jj + 2 * hi;           // this half-wave's edge pair: ea, ea+1
      int da = __shfl(d, ea);
      int db = __shfl(d, ea + 1);
      uint2 qa = *(const uint2*)(xh + (size_t)da * 128 + col4);
      uint2 qb = *(const uint2*)(xh + (size_t)db * 128 + col4);
      // interleave edge pair into half2 per column
      f16x2 X0 = u2h(__builtin_amdgcn_perm(qb.x, qa.x, 0x05040100u));
      f16x2 X1 = u2h(__builtin_amdgcn_perm(qb.x, qa.x, 0x07060302u));
      f16x2 X2 = u2h(__builtin_amdgcn_perm(qb.y, qa.y, 0x05040100u));
      f16x2 X3 = u2h(__builtin_amdgcn_perm(qb.y, qa.y, 0x07060302u));
#pragma unroll
      for (int h = 0; h < 8; ++h) {
        unsigned int wq = *(const unsigned int*)(wb + h * 72 + ea);   // w[h][ea..ea+1]
        f16x2 W = u2h(wq);
        acc[h][0] = dot2f(W, X0, acc[h][0]);
        acc[h][1] = dot2f(W, X1, acc[h][1]);
        acc[h][2] = dot2f(W, X2, acc[h][2]);
        acc[h][3] = dot2f(W, X3, acc[h][3]);
      }
    }
    for (; jj < cnt; ++jj) {          // tail edges: hi==0 half covers all 128 cols
      int dj = __shfl(d, jj);
      uint2 q = *(const uint2*)(xh + (size_t)dj * 128 + col4);
      if (hi == 0) {
        f16x2 x01 = u2h(q.x), x23 = u2h(q.y);
#pragma unroll
        for (int h = 0; h < 8; ++h) {
          float wh = __half2float(wb[h * 72 + jj]);
          acc[h][0] += wh * (float)x01[0];
          acc[h][1] += wh * (float)x01[1];
          acc[h][2] += wh * (float)x23[0];
          acc[h][3] += wh * (float)x23[1];
        }
      }
    }
  }

  // combine edge-parity halves (same cols both halves)
#pragma unroll
  for (int h = 0; h < 8; ++h)
#pragma unroll
    for (int cc = 0; cc < 4; ++cc) acc[h][cc] += __shfl_xor(acc[h][cc], 32);
  // full-wave rowsum reduce per head
#pragma unroll
  for (int off = 32; off > 0; off >>= 1)
#pragma unroll
    for (int h = 0; h < 8; ++h) rs[h] += __shfl_xor(rs[h], off);

  if (hi == 0) {
    f16* mp = msgx + (size_t)(node - c0) * 1024 + col4;
#pragma unroll
    for (int h = 0; h < 8; ++h) {
      float inv = 1.f / (rs[h] + EPS_DENOM);
      float2 st;
      ((__half2*)&st)[0] = __float22half2_rn(make_float2(acc[h][0] * inv, acc[h][1] * inv));
      ((__half2*)&st)[1] = __float22half2_rn(make_float2(acc[h][2] * inv, acc[h][3] * inv));
      *(float2*)(mp + h * 128) = st;
    }
  }
}

// ---------------- fused layer-1 GEMM + ELU + layer-2 GEMM, 32-row wave tiles ----------
// Wave = 32 rows (2 row-groups share every B-fragment -> 2x B reuse + latency amortize).
// 8 head-phases; per-wave-private LDS slice [32][68] (17.4 KB/block).
__global__ __launch_bounds__(256) void k_fusedgemm(
    const f16* __restrict__ msgx, const f16* __restrict__ w1t,
    const f16* __restrict__ w2t, const float* __restrict__ a2,
    f16* __restrict__ h2h, float* __restrict__ s2src, float* __restrict__ s2dst,
    int c0, int c1) {
  __shared__ f16 hl[4][32][68];   // per-wave slice; 68 = 64 + 4 pad
  int wave = threadIdx.x >> 6, lane = threadIdx.x & 63;
  int c = lane & 15, g = lane >> 4;
  int row0 = c0 + blockIdx.x * 128 + wave * 32;
  int ar0 = row0 + c;      if (ar0 > c1 - 1) ar0 = c1 - 1;
  int ar1 = row0 + 16 + c; if (ar1 > c1 - 1) ar1 = c1 - 1;

  f32x4 acc2[2][8];
#pragma unroll
  for (int jg = 0; jg < 2; ++jg)
#pragma unroll
    for (int t = 0; t < 8; ++t) acc2[jg][t] = (f32x4){0.f, 0.f, 0.f, 0.f};

#pragma unroll
  for (int h = 0; h < 8; ++h) {
    // stage 1: head h for both 16-row groups (bf shared)
    const f16* ap0 = msgx + ((size_t)(ar0 - c0) * 8 + h) * 128 + g * 8;
    const f16* ap1 = msgx + ((size_t)(ar1 - c0) * 8 + h) * 128 + g * 8;
    const f16* bp = w1t + (size_t)h * 8192;
    f32x4 acc[2][4];
#pragma unroll
    for (int jg = 0; jg < 2; ++jg)
#pragma unroll
      for (int t = 0; t < 4; ++t) acc[jg][t] = (f32x4){0.f, 0.f, 0.f, 0.f};
#pragma unroll
    for (int ks = 0; ks < 4; ++ks) {
      f16x8 af0 = *(const f16x8*)(ap0 + ks * 32);
      f16x8 af1 = *(const f16x8*)(ap1 + ks * 32);
#pragma unroll
      for (int t = 0; t < 4; ++t) {
        f16x8 bf = *(const f16x8*)(bp + (t * 16 + c) * 128 + ks * 32 + g * 8);
        acc[0][t] = __builtin_amdgcn_mfma_f32_16x16x32_f16(af0, bf, acc[0][t], 0, 0, 0);
        acc[1][t] = __builtin_amdgcn_mfma_f32_16x16x32_f16(af1, bf, acc[1][t], 0, 0, 0);
      }
    }
#pragma unroll
    for (int jg = 0; jg < 2; ++jg)
#pragma unroll
      for (int j = 0; j < 4; ++j)
#pragma unroll
        for (int t = 0; t < 4; ++t)
          hl[wave][jg * 16 + g * 4 + j][t * 16 + c] = (f16)elu_f(acc[jg][t][j]);

    // stage 2: accumulate this head's K=64 slice (cols h*64..) from wave-private LDS
#pragma unroll
    for (int ks2 = 0; ks2 < 2; ++ks2) {
      f16x8 af0 = *(const f16x8*)&hl[wave][c][ks2 * 32 + g * 8];
      f16x8 af1 = *(const f16x8*)&hl[wave][16 + c][ks2 * 32 + g * 8];
#pragma unroll
      for (int t = 0; t < 8; ++t) {
        f16x8 bf = *(const f16x8*)(w2t + (size_t)(t * 16 + c) * 512 + h * 64 + ks2 * 32 + g * 8);
        acc2[0][t] = __builtin_amdgcn_mfma_f32_16x16x32_f16(af0, bf, acc2[0][t], 0, 0, 0);
        acc2[1][t] = __builtin_amdgcn_mfma_f32_16x16x32_f16(af1, bf, acc2[1][t], 0, 0, 0);
      }
    }
  }

  float av0[8], av1[8];
#pragma unroll
  for (int t = 0; t < 8; ++t) {
    av0[t] = a2[t * 16 + c];
    av1[t] = a2[128 + t * 16 + c];
  }
#pragma unroll
  for (int jg = 0; jg < 2; ++jg)
#pragma unroll
    for (int j = 0; j < 4; ++j) {
      int r = row0 + jg * 16 + g * 4 + j;
      float s0 = 0.f, s1 = 0.f;
#pragma unroll
      for (int t = 0; t < 8; ++t) {
        float v = acc2[jg][t][j];
        if (r < c1) h2h[(size_t)r * 128 + t * 16 + c] = (f16)v;
        s0 += v * av0[t];
        s1 += v * av1[t];
      }
      s0 += __shfl_xor(s0, 1); s0 += __shfl_xor(s0, 2);
      s0 += __shfl_xor(s0, 4); s0 += __shfl_xor(s0, 8);
      s1 += __shfl_xor(s1, 1); s1 += __shfl_xor(s1, 2);
      s1 += __shfl_xor(s1, 4); s1 += __shfl_xor(s1, 8);
      if (c == 0 && r < c1) { s2src[r] = s0; s2dst[r] = s1; }
    }
}

// ---------------- layer-2 aggregation: cooperative-edge + deg==0 fallback + ELU -------
__global__ void k_agg2(const int* __restrict__ rp, const int* __restrict__ edge_dst,
                       const __half* __restrict__ h2h, const float* __restrict__ ssrc,
                       const float* __restrict__ sdst, const float* __restrict__ x,
                       float* __restrict__ out, int N) {
  int wv = (blockIdx.x * blockDim.x + threadIdx.x) >> 6;
  int lane = threadIdx.x & 63;
  if (wv >= N) return;
  int e0 = rp[wv], e1 = rp[wv + 1];
  if (e0 == e1) {
    float2 xv = *(const float2*)(x + (size_t)wv * 128 + 2 * lane);
    *(float2*)(out + (size_t)wv * 128 + 2 * lane) = make_float2(elu_f(xv.x), elu_f(xv.y));
    return;
  }
  float ss = ssrc[wv];
  int hi = lane >> 5;
  int colB = (lane & 31) << 2;
  float a0 = 0.f, a1 = 0.f, a2v = 0.f, a3 = 0.f, rsumL = 0.f;
  for (int base = e0; base < e1; base += 64) {
    int cnt = e1 - base; if (cnt > 64) cnt = 64;
    int d = 0; float w = 0.f;
    if (lane < cnt) {
      d = edge_dst[base + lane];
      w = edge_w(ss + sdst[d]);
    }
    rsumL += w;
    int jj = 0;
#pragma unroll 4
    for (; jj + 2 <= cnt; jj += 2) {
      int sel = jj + hi;
      int dj = __shfl(d, sel);
      float wj = __shfl(w, sel);
      float2 raw = *(const float2*)(h2h + ((size_t)dj << 7) + colB);
      float2 f01 = __half22float2(*(const __half2*)&raw.x);
      float2 f23 = __half22float2(*(const __half2*)&raw.y);
      a0 += wj * f01.x; a1 += wj * f01.y; a2v += wj * f23.x; a3 += wj * f23.y;
    }
    if (jj < cnt) {
      int dj = __shfl(d, jj);
      float wj = __shfl(w, jj);
      if (hi == 0) {
        float2 raw = *(const float2*)(h2h + ((size_t)dj << 7) + colB);
        float2 f01 = __half22float2(*(const __half2*)&raw.x);
        float2 f23 = __half22float2(*(const __half2*)&raw.y);
        a0 += wj * f01.x; a1 += wj * f01.y; a2v += wj * f23.x; a3 += wj * f23.y;
      }
    }
  }
  a0 += __shfl_xor(a0, 32); a1 += __shfl_xor(a1, 32);
  a2v += __shfl_xor(a2v, 32); a3 += __shfl_xor(a3, 32);
  float rsum = rsumL;
#pragma unroll
  for (int off = 32; off > 0; off >>= 1) rsum += __shfl_xor(rsum, off);
  float inv = 1.f / (rsum + EPS_DENOM);
  if (hi == 0) {
    *(float4*)(out + (size_t)wv * 128 + colB) =
        make_float4(elu_f(a0 * inv), elu_f(a1 * inv), elu_f(a2v * inv), elu_f(a3 * inv));
  }
}

extern "C" void kernel_launch(void* const* d_in, const int* in_sizes, int n_in,
                              void* d_out, int out_size, void* d_ws, size_t ws_size,
                              hipStream_t stream) {
  (void)n_in; (void)out_size;
  const float* x  = (const float*)d_in[0];
  const int*   ei = (const int*)d_in[1];
  const float* W1 = (const float*)d_in[2];
  const float* a1 = (const float*)d_in[3];
  const float* W2 = (const float*)d_in[4];
  const float* a2 = (const float*)d_in[5];
  float* out = (float*)d_out;
  const int N = in_sizes[0] / NFEAT;
  const int E = in_sizes[1] / 2;
  const int* src  = ei;
  const int* dstv = ei + E;

  int shift = 7;
  while ((((N - 1) >> shift) + 1) > MAXNB) ++shift;
  const int NB = ((N - 1) >> shift) + 1;

  // adaptive chunk count: smallest nc in {1,2,4,8,16,32} whose footprint fits ws_size
  int nc = 1;
  for (;;) {
    int cN = (N + nc - 1) / nc;
    size_t sz[15] = {
      (size_t)E * 8 > (size_t)cN * 2048 ? (size_t)E * 8 : (size_t)cN * 2048, // msgx/staging
      (size_t)N * 256,                // h2h
      (size_t)N * 256,                // xh
      (size_t)E * 4,                  // edge_dst
      (size_t)N * 32,                 // ssrc8
      (size_t)N * 16,                 // sdst8h
      (size_t)N * 4, (size_t)N * 4,   // s2src, s2dst
      (size_t)(N + 1) * 4,            // rp
      (size_t)(NB + 1) * 4, (size_t)(NB + 1) * 4, (size_t)(NB + 1) * 4,
      (size_t)NHEADS * 64 * 128 * 2,  // w1t
      (size_t)128 * 512 * 2,          // w2t
      (size_t)16 * 128 * 2            // uv16
    };
    size_t need = 0;
    for (int i = 0; i < 15; ++i) need += (sz[i] + 255) & ~(size_t)255;
    need += 4096;
    if (need <= ws_size || nc >= 32) break;
    nc <<= 1;
  }
  const int chunkN = (N + nc - 1) / nc;

  char* wp = (char*)d_ws;
  size_t off = 0;
  auto mk = [&](size_t bytes) -> void* {
    void* p = wp + off;
    off += (bytes + 255) & ~(size_t)255;
    return p;
  };
  size_t szR0 = (size_t)E * 8;
  if ((size_t)chunkN * 2048 > szR0) szR0 = (size_t)chunkN * 2048;
  f16*  msgx     = (f16*)mk(szR0);                   // aliases CSR staging
  int2* staging  = (int2*)msgx;
  f16*  h2h      = (f16*)mk((size_t)N * 128 * 2);
  f16*  xh       = (f16*)mk((size_t)N * 128 * 2);
  int*  edge_dst = (int*)mk((size_t)E * 4);
  float* ssrc8   = (float*)mk((size_t)N * 8 * 4);
  f16*  sdst8h   = (f16*)mk((size_t)N * 8 * 2);
  float* s2src   = (float*)mk((size_t)N * 4);
  float* s2dst   = (float*)mk((size_t)N * 4);
  int*  rp       = (int*)mk((size_t)(N + 1) * 4);
  int*  bhist    = (int*)mk((size_t)(NB + 1) * 4);
  int*  bbase    = (int*)mk((size_t)(NB + 1) * 4);
  int*  bcur     = (int*)mk((size_t)(NB + 1) * 4);
  f16*  w1t      = (f16*)mk((size_t)NHEADS * 64 * 128 * 2);
  f16*  w2t      = (f16*)mk((size_t)128 * 512 * 2);
  f16*  uv16     = (f16*)mk((size_t)16 * 128 * 2);

  // weight prep, then fused x-convert + scores (needs uv16)
  k_cvt_w<<<516, 256, 0, stream>>>(W1, W2, a1, w1t, w2t, uv16);
  k_prep_x<<<(N + 63) / 64, 256, 0, stream>>>(x, uv16, xh, ssrc8, sdst8h, N);

  // CSR build
  (void)hipMemsetAsync(bhist, 0, (size_t)NB * 4, stream);
  int binBlocks = (E + BIN_EPB - 1) / BIN_EPB;
  k_bhist<<<binBlocks, 256, 0, stream>>>(src, bhist, E, NB, shift);
  k_bscan<<<1, 1024, 0, stream>>>(bhist, bbase, bcur, rp, NB, N, E);
  k_binA<<<binBlocks, 256, 0, stream>>>(src, dstv, bcur, staging, E, NB, shift);
  k_binB<<<NB, 256, 0, stream>>>(staging, bbase, rp, edge_dst, N, shift);

  // layer 1 (all 8 heads) + fused GEMMs, per node-chunk
  for (int ch = 0; ch < nc; ++ch) {
    int c0 = ch * chunkN;
    if (c0 >= N) break;
    int c1 = c0 + chunkN; if (c1 > N) c1 = N;
    int cn = c1 - c0;
    k_aggx<<<(cn + 3) / 4, 256, 0, stream>>>(rp, edge_dst, xh, ssrc8, sdst8h, msgx, c0, c1);
    k_fusedgemm<<<(cn + 127) / 128, 256, 0, stream>>>(msgx, w1t, w2t, a2, h2h,
                                                      s2src, s2dst, c0, c1);
  }

  // layer-2 aggregation
  int wb = (N + 3) / 4;
  k_agg2<<<wb, 256, 0, stream>>>(rp, edge_dst, (const __half*)h2h, s2src, s2dst, x, out, N);
}

// Round 17
// 615.452 us; speedup vs baseline: 1.0718x; 1.0718x over previous
//
#include <hip/hip_runtime.h>
#include <hip/hip_fp16.h>

#define NFEAT 128
#define NHID 64
#define NOUT 128
#define NHEADS 8
#define ALPHA_SLOPE 0.2f
#define EPS_DENOM 1e-16f

#define MAXNB 1024
#define BIN_EPB 12288
#define BIN_CAP 6144

typedef _Float16 f16;
typedef f16 f16x2 __attribute__((ext_vector_type(2)));
typedef f16 f16x8 __attribute__((ext_vector_type(8)));
typedef float f32x4 __attribute__((ext_vector_type(4)));

static __device__ __forceinline__ float elu_f(float v) {
  return v > 0.f ? v : __expf(v) - 1.f;
}
static __device__ __forceinline__ float edge_w(float sc) {
  float lr = sc > 0.f ? sc : ALPHA_SLOPE * sc;
  return __expf(-lr);
}
static __device__ __forceinline__ f16x2 u2h(unsigned int u) {
  union { unsigned int u; f16x2 h; } c; c.u = u; return c.h;
}
static __device__ __forceinline__ float dot2f(f16x2 a, f16x2 b, float c) {
#if __has_builtin(__builtin_amdgcn_fdot2)
  return __builtin_amdgcn_fdot2(a, b, c, false);
#else
  return c + (float)a[0] * (float)b[0] + (float)a[1] * (float)b[1];
#endif
}

// region 0: W1 [8][128][64] -> w1t [8][64][128] fp16; region 1: W2 -> w2t [128][512] fp16;
// region 2: uv16[16][128] = {W1[h]@a1[h][:64], W1[h]@a1[h][64:]} (score identity)
__global__ void k_cvt_w(const float* __restrict__ W1, const float* __restrict__ W2,
                        const float* __restrict__ a1,
                        f16* __restrict__ w1t, f16* __restrict__ w2t,
                        f16* __restrict__ uv16) {
  int idx = blockIdx.x * 256 + threadIdx.x;
  if (idx < NHEADS * 128 * 64) {
    int h = idx >> 13, rem = idx & 8191, c = rem >> 7, k = rem & 127;
    w1t[idx] = (f16)W1[h * 8192 + k * 64 + c];
  } else if (idx < 2 * NHEADS * 128 * 64) {
    int j = idx - NHEADS * 128 * 64;
    int c = j >> 9, k = j & 511;
    w2t[j] = (f16)W2[k * 128 + c];
  } else {
    int id = idx - 2 * NHEADS * 128 * 64;
    if (id < 1024) {
      int h = id >> 7, k = id & 127;
      const float* wrow = W1 + h * 8192 + k * 64;
      const float* ah = a1 + h * 128;
      float u = 0.f, v = 0.f;
      for (int c = 0; c < 64; ++c) {
        float wv_ = wrow[c];
        u += wv_ * ah[c];
        v += wv_ * ah[64 + c];
      }
      uv16[h * 128 + k] = (f16)u;
      uv16[(8 + h) * 128 + k] = (f16)v;
    }
  }
}

// fused: x f32 -> xh fp16 AND [N,128]@[128,16] MFMA -> ssrc8 f32 / sdst8h fp16
__global__ __launch_bounds__(256) void k_prep_x(
    const float* __restrict__ x, const f16* __restrict__ uv16,
    f16* __restrict__ xh, float* __restrict__ ssrc8, f16* __restrict__ sdst8h, int N) {
  int wave = threadIdx.x >> 6, lane = threadIdx.x & 63;
  int c = lane & 15, g = lane >> 4;
  int row0 = blockIdx.x * 64 + wave * 16;
  f16x8 bf[4];
#pragma unroll
  for (int ks = 0; ks < 4; ++ks)
    bf[ks] = *(const f16x8*)(uv16 + c * 128 + ks * 32 + g * 8);
  int arow = row0 + c; if (arow > N - 1) arow = N - 1;
  const float* xp = x + (size_t)arow * 128 + g * 8;
  f16* xhp = xh + (size_t)arow * 128 + g * 8;
  f32x4 acc = (f32x4){0.f, 0.f, 0.f, 0.f};
#pragma unroll
  for (int ks = 0; ks < 4; ++ks) {
    float4 v0 = *(const float4*)(xp + ks * 32);
    float4 v1 = *(const float4*)(xp + ks * 32 + 4);
    f16x8 af;
    af[0] = (f16)v0.x; af[1] = (f16)v0.y; af[2] = (f16)v0.z; af[3] = (f16)v0.w;
    af[4] = (f16)v1.x; af[5] = (f16)v1.y; af[6] = (f16)v1.z; af[7] = (f16)v1.w;
    *(f16x8*)(xhp + ks * 32) = af;   // duplicate tail writes benign (same data)
    acc = __builtin_amdgcn_mfma_f32_16x16x32_f16(af, bf[ks], acc, 0, 0, 0);
  }
#pragma unroll
  for (int j = 0; j < 4; ++j) {
    int r = row0 + g * 4 + j;
    if (r < N) {
      if (c < 8) ssrc8[(size_t)r * 8 + c] = acc[j];
      else       sdst8h[(size_t)r * 8 + c - 8] = (f16)acc[j];
    }
  }
}

// ---------------- CSR build: 2-pass bucketed counting sort (packed 4B staging) -------
__global__ __launch_bounds__(256) void k_bhist(const int* __restrict__ src,
                                               int* __restrict__ bhist,
                                               int E, int NB, int shift) {
  __shared__ int h[MAXNB];
  int tid = threadIdx.x;
  for (int i = tid; i < NB; i += 256) h[i] = 0;
  __syncthreads();
  int base = blockIdx.x * BIN_EPB;
#pragma unroll 4
  for (int j = 0; j < BIN_EPB / 256; ++j) {
    int e = base + tid + j * 256;
    if (e < E) atomicAdd(&h[src[e] >> shift], 1);
  }
  __syncthreads();
  for (int i = tid; i < NB; i += 256)
    if (h[i]) atomicAdd(&bhist[i], h[i]);
}

__global__ __launch_bounds__(1024) void k_bscan(const int* __restrict__ bhist,
                                                int* __restrict__ bucket_base,
                                                int* __restrict__ bucket_cursor,
                                                int* __restrict__ rp,
                                                int NB, int N, int E) {
  __shared__ int sh[1024];
  int i = threadIdx.x;
  int v = (i < NB) ? bhist[i] : 0;
  sh[i] = v;
  __syncthreads();
  for (int off = 1; off < 1024; off <<= 1) {
    int add = (i >= off) ? sh[i - off] : 0;
    __syncthreads();
    sh[i] += add;
    __syncthreads();
  }
  if (i < NB) {
    int ex = sh[i] - v;
    bucket_base[i] = ex;
    bucket_cursor[i] = ex;
  }
  if (i == 0) {
    bucket_base[NB] = E;
    rp[N] = E;
  }
}

// scatter packed word ((dst << shift) | (src & mask)) into bucket-grouped staging
__global__ __launch_bounds__(256) void k_binA(const int* __restrict__ src,
                                              const int* __restrict__ dst,
                                              int* __restrict__ bucket_cursor,
                                              unsigned int* __restrict__ staging,
                                              int E, int NB, int shift) {
  __shared__ int h[MAXNB];
  int tid = threadIdx.x;
  for (int i = tid; i < NB; i += 256) h[i] = 0;
  __syncthreads();
  int base = blockIdx.x * BIN_EPB;
#pragma unroll 4
  for (int j = 0; j < BIN_EPB / 256; ++j) {
    int e = base + tid + j * 256;
    if (e < E) atomicAdd(&h[src[e] >> shift], 1);
  }
  __syncthreads();
  for (int i = tid; i < NB; i += 256)
    if (h[i]) h[i] = atomicAdd(&bucket_cursor[i], h[i]);
  __syncthreads();
  unsigned int rmask = (1u << shift) - 1u;
#pragma unroll 4
  for (int j = 0; j < BIN_EPB / 256; ++j) {
    int e = base + tid + j * 256;
    if (e < E) {
      int s = src[e];
      int slot = atomicAdd(&h[s >> shift], 1);
      staging[slot] = ((unsigned int)dst[e] << shift) | ((unsigned int)s & rmask);
    }
  }
}

__global__ __launch_bounds__(256) void k_binB(const unsigned int* __restrict__ staging,
                                              const int* __restrict__ bucket_base,
                                              int* __restrict__ rp,
                                              int* __restrict__ edge_dst,
                                              int N, int shift) {
  __shared__ unsigned int buf[BIN_CAP];
  __shared__ int rcnt[256], rsc[256];
  int tid = threadIdx.x;
  int b = blockIdx.x;
  int lo = bucket_base[b], hi = bucket_base[b + 1];
  int S = hi - lo;
  if (S > BIN_CAP) S = BIN_CAP;
  int R = 1 << shift;
  unsigned int rmask = (unsigned int)(R - 1);
  for (int i = tid; i < S; i += 256) buf[i] = staging[lo + i];
  if (tid < R) rcnt[tid] = 0;
  __syncthreads();
  for (int i = tid; i < S; i += 256) atomicAdd(&rcnt[buf[i] & rmask], 1);
  __syncthreads();
  if (tid < R) rsc[tid] = rcnt[tid];
  __syncthreads();
  for (int off = 1; off < 256; off <<= 1) {
    int add = (tid >= off && tid < R) ? rsc[tid - off] : 0;
    __syncthreads();
    if (tid < R) rsc[tid] += add;
    __syncthreads();
  }
  int row0 = b << shift;
  if (tid < R) {
    int ex = rsc[tid] - rcnt[tid];
    rcnt[tid] = ex;
    if (row0 + tid < N) rp[row0 + tid] = lo + ex;
  }
  __syncthreads();
  for (int i = tid; i < S; i += 256) {
    unsigned int wd = buf[i];
    int r = (int)(wd & rmask);
    int k = atomicAdd(&rcnt[r], 1);
    edge_dst[lo + k] = (int)(wd >> shift);
  }
}

// ---------------- layer-1 shared-x aggregation: ALL 8 heads, dot2-packed K ------------
// (R15 version — full wave per edge-quad; lane covers 2 cols; 4B/lane x-gather)
__global__ __launch_bounds__(256) void k_aggx(
    const int* __restrict__ rp, const int* __restrict__ edge_dst,
    const f16* __restrict__ xh, const float* __restrict__ ssrc8,
    const f16* __restrict__ sdst8h, f16* __restrict__ msgx, int c0, int c1) {
  __shared__ __half wT[4][8][72];   // per-wave transposed weights; 72 = 64 + 8 pad
  int wave = threadIdx.x >> 6;
  int lane = threadIdx.x & 63;
  int node = c0 + blockIdx.x * 4 + wave;
  if (node >= c1) return;             // safe: no __syncthreads below
  int e0 = rp[node], e1 = rp[node + 1];
  int col2 = lane * 2;
  float4 sA = *(const float4*)(ssrc8 + (size_t)node * 8);
  float4 sB = *(const float4*)(ssrc8 + (size_t)node * 8 + 4);
  float acc[8][2];
#pragma unroll
  for (int h = 0; h < 8; ++h) { acc[h][0] = 0.f; acc[h][1] = 0.f; }
  float rs[8];
#pragma unroll
  for (int h = 0; h < 8; ++h) rs[h] = 0.f;
  __half* wb = &wT[wave][0][0];   // head stride 72

  for (int base = e0; base < e1; base += 64) {
    int cnt = e1 - base; if (cnt > 64) cnt = 64;
    int d = 0;
    float w0 = 0.f, w1 = 0.f, w2 = 0.f, w3 = 0.f, w4 = 0.f, w5 = 0.f, w6 = 0.f, w7 = 0.f;
    if (lane < cnt) {
      d = edge_dst[base + lane];
      f16x8 dv = *(const f16x8*)(sdst8h + (size_t)d * 8);
      w0 = edge_w(sA.x + (float)dv[0]); w1 = edge_w(sA.y + (float)dv[1]);
      w2 = edge_w(sA.z + (float)dv[2]); w3 = edge_w(sA.w + (float)dv[3]);
      w4 = edge_w(sB.x + (float)dv[4]); w5 = edge_w(sB.y + (float)dv[5]);
      w6 = edge_w(sB.z + (float)dv[6]); w7 = edge_w(sB.w + (float)dv[7]);
      rs[0] += w0; rs[1] += w1; rs[2] += w2; rs[3] += w3;
      rs[4] += w4; rs[5] += w5; rs[6] += w6; rs[7] += w7;
    }
    wb[0 * 72 + lane] = __float2half(w0);
    wb[1 * 72 + lane] = __float2half(w1);
    wb[2 * 72 + lane] = __float2half(w2);
    wb[3 * 72 + lane] = __float2half(w3);
    wb[4 * 72 + lane] = __float2half(w4);
    wb[5 * 72 + lane] = __float2half(w5);
    wb[6 * 72 + lane] = __float2half(w6);
    wb[7 * 72 + lane] = __float2half(w7);
    __threadfence_block();            // order per-wave LDS write -> read

    int jj = 0;
    for (; jj + 4 <= cnt; jj += 4) {
      int d0 = __shfl(d, jj),     d1 = __shfl(d, jj + 1);
      int d2 = __shfl(d, jj + 2), d3 = __shfl(d, jj + 3);
      unsigned int ua = *(const unsigned int*)(xh + (size_t)d0 * 128 + col2);
      unsigned int ub = *(const unsigned int*)(xh + (size_t)d1 * 128 + col2);
      unsigned int uc = *(const unsigned int*)(xh + (size_t)d2 * 128 + col2);
      unsigned int ud = *(const unsigned int*)(xh + (size_t)d3 * 128 + col2);
      // interleave rows into (edge0,edge1) half2 per column
      f16x2 XA0 = u2h(__builtin_amdgcn_perm(ub, ua, 0x05040100u));
      f16x2 XA1 = u2h(__builtin_amdgcn_perm(ub, ua, 0x07060302u));
      f16x2 XB0 = u2h(__builtin_amdgcn_perm(ud, uc, 0x05040100u));
      f16x2 XB1 = u2h(__builtin_amdgcn_perm(ud, uc, 0x07060302u));
#pragma unroll
      for (int h = 0; h < 8; ++h) {
        uint2 wq = *(const uint2*)(wb + h * 72 + jj);   // w[h][jj..jj+3], broadcast
        f16x2 WA = u2h(wq.x), WB = u2h(wq.y);
        acc[h][0] = dot2f(WA, XA0, acc[h][0]);
        acc[h][0] = dot2f(WB, XB0, acc[h][0]);
        acc[h][1] = dot2f(WA, XA1, acc[h][1]);
        acc[h][1] = dot2f(WB, XB1, acc[h][1]);
      }
    }
    for (; jj < cnt; ++jj) {          // tail edges (scalar)
      int dj = __shfl(d, jj);
      unsigned int u = *(const unsigned int*)(xh + (size_t)dj * 128 + col2);
      f16x2 xv = u2h(u);
      float x0 = (float)xv[0], x1 = (float)xv[1];
#pragma unroll
      for (int h = 0; h < 8; ++h) {
        float wh = __half2float(wb[h * 72 + jj]);
        acc[h][0] += wh * x0;
        acc[h][1] += wh * x1;
      }
    }
  }

  // full-wave rowsum reduce per head
#pragma unroll
  for (int off = 32; off > 0; off >>= 1)
#pragma unroll
    for (int h = 0; h < 8; ++h) rs[h] += __shfl_xor(rs[h], off);

  f16* mp = msgx + (size_t)(node - c0) * 1024 + col2;
#pragma unroll
  for (int h = 0; h < 8; ++h) {
    float inv = 1.f / (rs[h] + EPS_DENOM);
    __half2 st = __float22half2_rn(make_float2(acc[h][0] * inv, acc[h][1] * inv));
    *(__half2*)(mp + h * 128) = st;
  }
}

// ---------------- fused layer-1 GEMM + ELU + layer-2 GEMM, 32-row wave tiles ----------
__global__ __launch_bounds__(256) void k_fusedgemm(
    const f16* __restrict__ msgx, const f16* __restrict__ w1t,
    const f16* __restrict__ w2t, const float* __restrict__ a2,
    f16* __restrict__ h2h, float* __restrict__ s2src, float* __restrict__ s2dst,
    int c0, int c1) {
  __shared__ f16 hl[4][32][68];   // per-wave slice; 68 = 64 + 4 pad
  int wave = threadIdx.x >> 6, lane = threadIdx.x & 63;
  int c = lane & 15, g = lane >> 4;
  int row0 = c0 + blockIdx.x * 128 + wave * 32;
  int ar0 = row0 + c;      if (ar0 > c1 - 1) ar0 = c1 - 1;
  int ar1 = row0 + 16 + c; if (ar1 > c1 - 1) ar1 = c1 - 1;

  f32x4 acc2[2][8];
#pragma unroll
  for (int jg = 0; jg < 2; ++jg)
#pragma unroll
    for (int t = 0; t < 8; ++t) acc2[jg][t] = (f32x4){0.f, 0.f, 0.f, 0.f};

#pragma unroll
  for (int h = 0; h < 8; ++h) {
    const f16* ap0 = msgx + ((size_t)(ar0 - c0) * 8 + h) * 128 + g * 8;
    const f16* ap1 = msgx + ((size_t)(ar1 - c0) * 8 + h) * 128 + g * 8;
    const f16* bp = w1t + (size_t)h * 8192;
    f32x4 acc[2][4];
#pragma unroll
    for (int jg = 0; jg < 2; ++jg)
#pragma unroll
      for (int t = 0; t < 4; ++t) acc[jg][t] = (f32x4){0.f, 0.f, 0.f, 0.f};
#pragma unroll
    for (int ks = 0; ks < 4; ++ks) {
      f16x8 af0 = *(const f16x8*)(ap0 + ks * 32);
      f16x8 af1 = *(const f16x8*)(ap1 + ks * 32);
#pragma unroll
      for (int t = 0; t < 4; ++t) {
        f16x8 bf = *(const f16x8*)(bp + (t * 16 + c) * 128 + ks * 32 + g * 8);
        acc[0][t] = __builtin_amdgcn_mfma_f32_16x16x32_f16(af0, bf, acc[0][t], 0, 0, 0);
        acc[1][t] = __builtin_amdgcn_mfma_f32_16x16x32_f16(af1, bf, acc[1][t], 0, 0, 0);
      }
    }
#pragma unroll
    for (int jg = 0; jg < 2; ++jg)
#pragma unroll
      for (int j = 0; j < 4; ++j)
#pragma unroll
        for (int t = 0; t < 4; ++t)
          hl[wave][jg * 16 + g * 4 + j][t * 16 + c] = (f16)elu_f(acc[jg][t][j]);

#pragma unroll
    for (int ks2 = 0; ks2 < 2; ++ks2) {
      f16x8 af0 = *(const f16x8*)&hl[wave][c][ks2 * 32 + g * 8];
      f16x8 af1 = *(const f16x8*)&hl[wave][16 + c][ks2 * 32 + g * 8];
#pragma unroll
      for (int t = 0; t < 8; ++t) {
        f16x8 bf = *(const f16x8*)(w2t + (size_t)(t * 16 + c) * 512 + h * 64 + ks2 * 32 + g * 8);
        acc2[0][t] = __builtin_amdgcn_mfma_f32_16x16x32_f16(af0, bf, acc2[0][t], 0, 0, 0);
        acc2[1][t] = __builtin_amdgcn_mfma_f32_16x16x32_f16(af1, bf, acc2[1][t], 0, 0, 0);
      }
    }
  }

  float av0[8], av1[8];
#pragma unroll
  for (int t = 0; t < 8; ++t) {
    av0[t] = a2[t * 16 + c];
    av1[t] = a2[128 + t * 16 + c];
  }
#pragma unroll
  for (int jg = 0; jg < 2; ++jg)
#pragma unroll
    for (int j = 0; j < 4; ++j) {
      int r = row0 + jg * 16 + g * 4 + j;
      float s0 = 0.f, s1 = 0.f;
#pragma unroll
      for (int t = 0; t < 8; ++t) {
        float v = acc2[jg][t][j];
        if (r < c1) h2h[(size_t)r * 128 + t * 16 + c] = (f16)v;
        s0 += v * av0[t];
        s1 += v * av1[t];
      }
      s0 += __shfl_xor(s0, 1); s0 += __shfl_xor(s0, 2);
      s0 += __shfl_xor(s0, 4); s0 += __shfl_xor(s0, 8);
      s1 += __shfl_xor(s1, 1); s1 += __shfl_xor(s1, 2);
      s1 += __shfl_xor(s1, 4); s1 += __shfl_xor(s1, 8);
      if (c == 0 && r < c1) { s2src[r] = s0; s2dst[r] = s1; }
    }
}

// ---------------- layer-2 aggregation: cooperative-edge + deg==0 fallback + ELU -------
__global__ void k_agg2(const int* __restrict__ rp, const int* __restrict__ edge_dst,
                       const __half* __restrict__ h2h, const float* __restrict__ ssrc,
                       const float* __restrict__ sdst, const float* __restrict__ x,
                       float* __restrict__ out, int N) {
  int wv = (blockIdx.x * blockDim.x + threadIdx.x) >> 6;
  int lane = threadIdx.x & 63;
  if (wv >= N) return;
  int e0 = rp[wv], e1 = rp[wv + 1];
  if (e0 == e1) {
    float2 xv = *(const float2*)(x + (size_t)wv * 128 + 2 * lane);
    *(float2*)(out + (size_t)wv * 128 + 2 * lane) = make_float2(elu_f(xv.x), elu_f(xv.y));
    return;
  }
  float ss = ssrc[wv];
  int hi = lane >> 5;
  int colB = (lane & 31) << 2;
  float a0 = 0.f, a1 = 0.f, a2v = 0.f, a3 = 0.f, rsumL = 0.f;
  for (int base = e0; base < e1; base += 64) {
    int cnt = e1 - base; if (cnt > 64) cnt = 64;
    int d = 0; float w = 0.f;
    if (lane < cnt) {
      d = edge_dst[base + lane];
      w = edge_w(ss + sdst[d]);
    }
    rsumL += w;
    int jj = 0;
#pragma unroll 4
    for (; jj + 2 <= cnt; jj += 2) {
      int sel = jj + hi;
      int dj = __shfl(d, sel);
      float wj = __shfl(w, sel);
      float2 raw = *(const float2*)(h2h + ((size_t)dj << 7) + colB);
      float2 f01 = __half22float2(*(const __half2*)&raw.x);
      float2 f23 = __half22float2(*(const __half2*)&raw.y);
      a0 += wj * f01.x; a1 += wj * f01.y; a2v += wj * f23.x; a3 += wj * f23.y;
    }
    if (jj < cnt) {
      int dj = __shfl(d, jj);
      float wj = __shfl(w, jj);
      if (hi == 0) {
        float2 raw = *(const float2*)(h2h + ((size_t)dj << 7) + colB);
        float2 f01 = __half22float2(*(const __half2*)&raw.x);
        float2 f23 = __half22float2(*(const __half2*)&raw.y);
        a0 += wj * f01.x; a1 += wj * f01.y; a2v += wj * f23.x; a3 += wj * f23.y;
      }
    }
  }
  a0 += __shfl_xor(a0, 32); a1 += __shfl_xor(a1, 32);
  a2v += __shfl_xor(a2v, 32); a3 += __shfl_xor(a3, 32);
  float rsum = rsumL;
#pragma unroll
  for (int off = 32; off > 0; off >>= 1) rsum += __shfl_xor(rsum, off);
  float inv = 1.f / (rsum + EPS_DENOM);
  if (hi == 0) {
    *(float4*)(out + (size_t)wv * 128 + colB) =
        make_float4(elu_f(a0 * inv), elu_f(a1 * inv), elu_f(a2v * inv), elu_f(a3 * inv));
  }
}

extern "C" void kernel_launch(void* const* d_in, const int* in_sizes, int n_in,
                              void* d_out, int out_size, void* d_ws, size_t ws_size,
                              hipStream_t stream) {
  (void)n_in; (void)out_size;
  const float* x  = (const float*)d_in[0];
  const int*   ei = (const int*)d_in[1];
  const float* W1 = (const float*)d_in[2];
  const float* a1 = (const float*)d_in[3];
  const float* W2 = (const float*)d_in[4];
  const float* a2 = (const float*)d_in[5];
  float* out = (float*)d_out;
  const int N = in_sizes[0] / NFEAT;
  const int E = in_sizes[1] / 2;
  const int* src  = ei;
  const int* dstv = ei + E;

  int shift = 7;
  while ((((N - 1) >> shift) + 1) > MAXNB) ++shift;
  const int NB = ((N - 1) >> shift) + 1;

  // adaptive chunk count: smallest nc in {1,2,4,8,16,32} whose footprint fits ws_size
  int nc = 1;
  for (;;) {
    int cN = (N + nc - 1) / nc;
    size_t sz[15] = {
      (size_t)E * 4 > (size_t)cN * 2048 ? (size_t)E * 4 : (size_t)cN * 2048, // msgx/staging
      (size_t)N * 256,                // h2h
      (size_t)N * 256,                // xh
      (size_t)E * 4,                  // edge_dst
      (size_t)N * 32,                 // ssrc8
      (size_t)N * 16,                 // sdst8h
      (size_t)N * 4, (size_t)N * 4,   // s2src, s2dst
      (size_t)(N + 1) * 4,            // rp
      (size_t)(NB + 1) * 4, (size_t)(NB + 1) * 4, (size_t)(NB + 1) * 4,
      (size_t)NHEADS * 64 * 128 * 2,  // w1t
      (size_t)128 * 512 * 2,          // w2t
      (size_t)16 * 128 * 2            // uv16
    };
    size_t need = 0;
    for (int i = 0; i < 15; ++i) need += (sz[i] + 255) & ~(size_t)255;
    need += 4096;
    if (need <= ws_size || nc >= 32) break;
    nc <<= 1;
  }
  const int chunkN = (N + nc - 1) / nc;

  char* wp = (char*)d_ws;
  size_t off = 0;
  auto mk = [&](size_t bytes) -> void* {
    void* p = wp + off;
    off += (bytes + 255) & ~(size_t)255;
    return p;
  };
  size_t szR0 = (size_t)E * 4;
  if ((size_t)chunkN * 2048 > szR0) szR0 = (size_t)chunkN * 2048;
  f16*  msgx     = (f16*)mk(szR0);                   // aliases CSR staging
  unsigned int* staging = (unsigned int*)msgx;
  f16*  h2h      = (f16*)mk((size_t)N * 128 * 2);
  f16*  xh       = (f16*)mk((size_t)N * 128 * 2);
  int*  edge_dst = (int*)mk((size_t)E * 4);
  float* ssrc8   = (float*)mk((size_t)N * 8 * 4);
  f16*  sdst8h   = (f16*)mk((size_t)N * 8 * 2);
  float* s2src   = (float*)mk((size_t)N * 4);
  float* s2dst   = (float*)mk((size_t)N * 4);
  int*  rp       = (int*)mk((size_t)(N + 1) * 4);
  int*  bhist    = (int*)mk((size_t)(NB + 1) * 4);
  int*  bbase    = (int*)mk((size_t)(NB + 1) * 4);
  int*  bcur     = (int*)mk((size_t)(NB + 1) * 4);
  f16*  w1t      = (f16*)mk((size_t)NHEADS * 64 * 128 * 2);
  f16*  w2t      = (f16*)mk((size_t)128 * 512 * 2);
  f16*  uv16     = (f16*)mk((size_t)16 * 128 * 2);

  // weight prep, then fused x-convert + scores (needs uv16)
  k_cvt_w<<<516, 256, 0, stream>>>(W1, W2, a1, w1t, w2t, uv16);
  k_prep_x<<<(N + 63) / 64, 256, 0, stream>>>(x, uv16, xh, ssrc8, sdst8h, N);

  // CSR build
  (void)hipMemsetAsync(bhist, 0, (size_t)NB * 4, stream);
  int binBlocks = (E + BIN_EPB - 1) / BIN_EPB;
  k_bhist<<<binBlocks, 256, 0, stream>>>(src, bhist, E, NB, shift);
  k_bscan<<<1, 1024, 0, stream>>>(bhist, bbase, bcur, rp, NB, N, E);
  k_binA<<<binBlocks, 256, 0, stream>>>(src, dstv, bcur, staging, E, NB, shift);
  k_binB<<<NB, 256, 0, stream>>>(staging, bbase, rp, edge_dst, N, shift);

  // layer 1 (all 8 heads) + fused GEMMs, per node-chunk
  for (int ch = 0; ch < nc; ++ch) {
    int c0 = ch * chunkN;
    if (c0 >= N) break;
    int c1 = c0 + chunkN; if (c1 > N) c1 = N;
    int cn = c1 - c0;
    k_aggx<<<(cn + 3) / 4, 256, 0, stream>>>(rp, edge_dst, xh, ssrc8, sdst8h, msgx, c0, c1);
    k_fusedgemm<<<(cn + 127) / 128, 256, 0, stream>>>(msgx, w1t, w2t, a2, h2h,
                                                      s2src, s2dst, c0, c1);
  }

  // layer-2 aggregation
  int wb = (N + 3) / 4;
  k_agg2<<<wb, 256, 0, stream>>>(rp, edge_dst, (const __half*)h2h, s2src, s2dst, x, out, N);
}